// Round 2
// baseline (733.535 us; speedup 1.0000x reference)
//
#include <hip/hip_runtime.h>
#include <hip/hip_fp16.h>

// B=256,S=256,T=32,H=512,E=128,V=1000,A=8,NT=80.
// Decoder is dead code (softmax shift-invariance over S) -> outputs tiled pa/pt.
// 256 serial LSTM steps: 16 batch-groups x (16 rows, 16 wgs); Wh in registers,
// x-part precomputed (P = embed@Wi.T + b, fp32 gather).
// History: R4 best protocol (3.1us/step = sync 1.6 + compute 1.5). R5-R10: all
// flag-protocol variants regressed/hung. R11: fp16 single-plane MFMA (808.9us).
// R12: eliminate flag protocol -- enc_out is the write-once h-exchange buffer,
// NaN-XOR-encoded stores (h2 ^ 0x7FFF7FFF; dword==0 unreachable since gate math
// can't produce fp16 NaN). Consumers poll their own stage loads: chain =
// store -> visible -> detect -> LDS -> MFMA (~2 coherent RTs vs R4's ~4).
// R13 (this = R12 resubmit; both prior rounds were infra failures, no data):
// + s_sleep(1) throttle in the poll retry loop. All 256 threads x 16 wgs/group
// spin on 64B sc0sc1 loads; unthrottled worst-case poll traffic ~tens of TB/s
// could self-interfere with the producers' stores. 64-cycle backoff (~27ns)
// is negligible vs the ~150-400ns visibility RT. Numerics identical to R11.

#define Sv 256
#define Tv 32
#define Hv 512
#define KT 16          // k-tiles of 32 over K=512 (h only; x-part via P gather)
#define LDSA 520       // padded row stride in halfs (1040B = 65*16, b128-aligned)
#define GM 16          // batch rows per group

#define ENC_KEY 0x7FFF7FFFu   // per-half 0x7FFF = fp16 NaN: unreachable by gate math

typedef _Float16 half8 __attribute__((ext_vector_type(8)));
typedef __attribute__((ext_vector_type(4))) float f32x4;
typedef __attribute__((ext_vector_type(4))) unsigned uint4v;

__device__ __forceinline__ float sigm(float x) { return 1.0f / (1.0f + __expf(-x)); }
__device__ __forceinline__ float tanh_fast(float x) {
  x = fminf(15.f, fmaxf(-15.f, x));
  float e = __expf(2.f * x);
  return (e - 1.f) / (e + 1.f);
}

// Coherent (device-scope) 16B load: bypasses L1/L2, pipelines like any vmem op.
__device__ __forceinline__ uint4v ld_b128_sys(const void* p) {
  uint4v r;
  asm volatile("global_load_dwordx4 %0, %1, off sc0 sc1" : "=v"(r) : "v"(p));
  return r;
}

__device__ __forceinline__ unsigned umin4(uint4v r) {
  unsigned a = r[0] < r[1] ? r[0] : r[1];
  unsigned b = r[2] < r[3] ? r[2] : r[3];
  return a < b ? a : b;
}

// ---- P[v][n] = sum_k embed[v][k]*Wi[n][k] + be[n], fp32. 250 blocks x 4 tokens.
__global__ __launch_bounds__(256)
void build_P(const float* __restrict__ embed, const float* __restrict__ Wi,
             const float* __restrict__ be, float* __restrict__ P)
{
  __shared__ float ev[4][128];
  const int tid = threadIdx.x;
  const int v0  = blockIdx.x * 4;
#pragma unroll
  for (int i = 0; i < 2; ++i) {
    int e = tid + i * 256;
    ev[e >> 7][e & 127] = embed[(v0 + (e >> 7)) * 128 + (e & 127)];
  }
  __syncthreads();
#pragma unroll 1
  for (int cc = 0; cc < 8; ++cc) {
    int n = cc * 256 + tid;
    float b = be[n];
    float a0 = b, a1 = b, a2 = b, a3 = b;
    const f32x4* w = (const f32x4*)(Wi + n * 128);
#pragma unroll
    for (int k4 = 0; k4 < 32; ++k4) {
      f32x4 wv = w[k4];
#pragma unroll
      for (int j = 0; j < 4; ++j) {
        float wj = wv[j];
        int k = k4 * 4 + j;
        a0 += wj * ev[0][k]; a1 += wj * ev[1][k];
        a2 += wj * ev[2][k]; a3 += wj * ev[3][k];
      }
    }
    P[(size_t)(v0 + 0) * 2048 + n] = a0;
    P[(size_t)(v0 + 1) * 2048 + n] = a1;
    P[(size_t)(v0 + 2) * 2048 + n] = a2;
    P[(size_t)(v0 + 3) * 2048 + n] = a3;
  }
}

// enc_out doubles as the h-exchange buffer: write-once per (row, step), each
// dword stored XOR ENC_KEY via agent-scope atomic (never 0). Consumers poll
// their own b128 stage loads until all dwords nonzero, decode, write LDS.
__global__ __launch_bounds__(256, 1)
void lstm_enc(const int* __restrict__ enc_in, const float* __restrict__ P,
              const float* __restrict__ Wh, __half* __restrict__ enc_out)
{
  __shared__ __attribute__((aligned(16))) _Float16 Ah[GM][LDSA];
  __shared__ float zbuf[4][GM][37];

  const int tid  = threadIdx.x;
  const int wg   = blockIdx.x;
  const int g    = wg & 15;   // group (members share wg%8 -> same XCD heuristically; perf only)
  const int cb   = wg >> 4;   // column block: owns z-cols [q*512 + cb*32, +32) per gate q
  const int wave = tid >> 6;  // wave == gate q (0=i,1=f,2=g,3=o)
  const int lane = tid & 63;
  const int m16  = lane & 15;
  const int qd   = lane >> 4;

  // ---- Wh fragments in registers (fp16): lane holds W'[n][k] for
  // n = wave*512 + cb*32 + nt*16 + m16, k = kt*32 + qd*8 + j (j=0..7).
  half8 wf[KT][2];
#pragma unroll
  for (int kt = 0; kt < KT; ++kt) {
#pragma unroll
    for (int nt = 0; nt < 2; ++nt) {
      int n  = wave * 512 + cb * 32 + nt * 16 + m16;
      int k0 = kt * 32 + qd * 8;
      const float* src = Wh + (size_t)n * Hv + k0;
      f32x4 f0 = *(const f32x4*)(src);
      f32x4 f1 = *(const f32x4*)(src + 4);
      half8 w;
      w[0] = (_Float16)f0[0]; w[1] = (_Float16)f0[1];
      w[2] = (_Float16)f0[2]; w[3] = (_Float16)f0[3];
      w[4] = (_Float16)f1[0]; w[5] = (_Float16)f1[1];
      w[6] = (_Float16)f1[2]; w[7] = (_Float16)f1[3];
      wf[kt][nt] = w;
    }
  }

  // gates-phase mapping: thread owns (row gr, cols gj, gj+1); c-state in regs
  const int gr = tid >> 4;
  const int gj = (tid & 15) * 2;
  float c0 = 0.f, c1 = 0.f;

  // ---- P prefetch for s=0 (acc-layout rows r0..r0+3, cols ncol, ncol+16)
  const int r0   = qd * 4;
  const int ncol = wave * 512 + cb * 32 + m16;
  float px0[4], px1[4];
#pragma unroll
  for (int rr = 0; rr < 4; ++rr) {
    int tk  = enc_in[(g * GM + r0 + rr) * Sv + 0];
    px0[rr] = P[(size_t)tk * 2048 + ncol];
    px1[rr] = P[(size_t)tk * 2048 + ncol + 16];
  }

  // ---- stage geometry: thread loads 4 chunks, chunk j = row j*4+rw,
  // halfs [colh, colh+8) of the previous step's enc_out row.
  const int rw   = tid >> 6;
  const int colh = (tid & 63) * 8;
  const size_t rowstride = (size_t)Sv * Hv;  // halfs per batch row
  size_t rb[4];
#pragma unroll
  for (int j = 0; j < 4; ++j)
    rb[j] = (size_t)(g * GM + j * 4 + rw) * rowstride + colh;

  const uint4v K4 = {ENC_KEY, ENC_KEY, ENC_KEY, ENC_KEY};

#pragma unroll 1
  for (int s = 0; s < Sv; ++s) {
    if (s > 0) {
      // ---- poll-stage: h(step s-1) lives at enc_out[row][s-1][:], encoded.
      const __half* sp = enc_out + (size_t)(s - 1) * Hv;
      const void* p0 = sp + rb[0];
      const void* p1 = sp + rb[1];
      const void* p2 = sp + rb[2];
      const void* p3 = sp + rb[3];
      uint4v ra, rbv, rc, rd;
      unsigned ok = 0;
      do {
        if (!(ok & 1u)) ra  = ld_b128_sys(p0);
        if (!(ok & 2u)) rbv = ld_b128_sys(p1);
        if (!(ok & 4u)) rc  = ld_b128_sys(p2);
        if (!(ok & 8u)) rd  = ld_b128_sys(p3);
        asm volatile("s_waitcnt vmcnt(0)"
                     : "+v"(ra), "+v"(rbv), "+v"(rc), "+v"(rd)
                     :: "memory");
        if (umin4(ra))  ok |= 1u;
        if (umin4(rbv)) ok |= 2u;
        if (umin4(rc))  ok |= 4u;
        if (umin4(rd))  ok |= 8u;
        if (ok != 15u) __builtin_amdgcn_s_sleep(1);  // ~64cy backoff: caps poll traffic
      } while (ok != 15u);
      // decode (exact) + LDS write in fragment-native layout
      *(uint4v*)&Ah[0 * 4 + rw][colh] = ra  ^ K4;
      *(uint4v*)&Ah[1 * 4 + rw][colh] = rbv ^ K4;
      *(uint4v*)&Ah[2 * 4 + rw][colh] = rc  ^ K4;
      *(uint4v*)&Ah[3 * 4 + rw][colh] = rd  ^ K4;
    }
    __syncthreads();   // B1: stage complete

    // ---- MFMA: z_h = A @ Wh^T (fp16 inputs, fp32 accumulate). s=0: A=0.
    f32x4 acc0 = {0.f, 0.f, 0.f, 0.f};
    f32x4 acc1 = {0.f, 0.f, 0.f, 0.f};
    if (s > 0) {
#pragma unroll
      for (int kt = 0; kt < KT; ++kt) {
        half8 a = *(const half8*)&Ah[m16][kt * 32 + qd * 8];
        acc0 = __builtin_amdgcn_mfma_f32_16x16x32_f16(a, wf[kt][0], acc0, 0, 0, 0);
        acc1 = __builtin_amdgcn_mfma_f32_16x16x32_f16(a, wf[kt][1], acc1, 0, 0, 0);
      }
    }
    // C/D layout: col = lane&15, row = (lane>>4)*4 + reg; add fp32 x-part (P)
#pragma unroll
    for (int rr = 0; rr < 4; ++rr) {
      zbuf[wave][r0 + rr][m16]      = acc0[rr] + px0[rr];
      zbuf[wave][r0 + rr][16 + m16] = acc1[rr] + px1[rr];
    }
    __syncthreads();   // B2: zbuf complete (also fences Ah reads vs next stage writes)

    // ---- gates for (gr, gj), (gr, gj+1)
    float i0 = zbuf[0][gr][gj], i1 = zbuf[0][gr][gj + 1];
    float f0g = zbuf[1][gr][gj], f1g = zbuf[1][gr][gj + 1];
    float g0 = zbuf[2][gr][gj], g1 = zbuf[2][gr][gj + 1];
    float o0 = zbuf[3][gr][gj], o1 = zbuf[3][gr][gj + 1];
    float cn0 = sigm(f0g) * c0 + sigm(i0) * tanh_fast(g0);
    float cn1 = sigm(f1g) * c1 + sigm(i1) * tanh_fast(g1);
    float hn0 = sigm(o0) * tanh_fast(cn0);
    float hn1 = sigm(o1) * tanh_fast(cn1);
    c0 = cn0; c1 = cn1;

    // ---- SINGLE encoded store: enc_out[row][s][col pair] = h2 ^ KEY
    // (agent scope -> visible past per-XCD L2; dword is never 0).
    __half2 h2;
    h2.x = __float2half(hn0);
    h2.y = __float2half(hn1);
    {
      unsigned pk = __builtin_bit_cast(unsigned, h2) ^ ENC_KEY;
      __hip_atomic_store(
          (unsigned*)(enc_out + ((size_t)(g * GM + gr) * Sv + s) * Hv + cb * 32 + gj),
          pk, __ATOMIC_RELAXED, __HIP_MEMORY_SCOPE_AGENT);
    }

    // ---- next-step P gather: issued now, completes under the next poll window
    if (s + 1 < Sv) {
      int sn = s + 1;
#pragma unroll
      for (int rr = 0; rr < 4; ++rr) {
        int tk  = enc_in[(g * GM + r0 + rr) * Sv + sn];
        px0[rr] = P[(size_t)tk * 2048 + ncol];
        px1[rr] = P[(size_t)tk * 2048 + ncol + 16];
      }
    }
  }
}

// One wg per batch row: scores = enc_out[b] @ We, softmax over S, ctx, then
// pa/pt dots tiled over T. fp32 math; enc_out is XOR-encoded fp16 -> decode.
__global__ __launch_bounds__(256)
void attn_out(const __half* __restrict__ enc_out, const float* __restrict__ Wf,
              const float* __restrict__ Wa, const float* __restrict__ ba,
              const float* __restrict__ Wt, const float* __restrict__ bt,
              float* __restrict__ out)
{
  __shared__ float We[512];
  __shared__ float sc[256];
  __shared__ float ctx[512];
  __shared__ float red[8];
  const int tid = threadIdx.x;
  const int b   = blockIdx.x;
  const int wv  = tid >> 6;
  const int ln  = tid & 63;

  We[tid] = Wf[tid];
  We[tid + 256] = Wf[tid + 256];
  __syncthreads();

  const uint4* r4 = (const uint4*)(enc_out + ((size_t)b * Sv + tid) * Hv);
  float a = 0.f;
#pragma unroll 4
  for (int k = 0; k < 64; ++k) {
    uint4 v = r4[k];
    v.x ^= ENC_KEY; v.y ^= ENC_KEY; v.z ^= ENC_KEY; v.w ^= ENC_KEY;
    float2 f0 = __half22float2(__builtin_bit_cast(__half2, v.x));
    float2 f1 = __half22float2(__builtin_bit_cast(__half2, v.y));
    float2 f2 = __half22float2(__builtin_bit_cast(__half2, v.z));
    float2 f3 = __half22float2(__builtin_bit_cast(__half2, v.w));
    const float* wp = &We[8 * k];
    a += f0.x * wp[0] + f0.y * wp[1] + f1.x * wp[2] + f1.y * wp[3]
       + f2.x * wp[4] + f2.y * wp[5] + f3.x * wp[6] + f3.y * wp[7];
  }

  float m = a;
  for (int off = 32; off; off >>= 1) m = fmaxf(m, __shfl_down(m, off));
  if (ln == 0) red[wv] = m;
  __syncthreads();
  if (tid == 0) red[4] = fmaxf(fmaxf(red[0], red[1]), fmaxf(red[2], red[3]));
  __syncthreads();
  float e = __expf(a - red[4]);
  float ssum = e;
  for (int off = 32; off; off >>= 1) ssum += __shfl_down(ssum, off);
  if (ln == 0) red[wv] = ssum;
  __syncthreads();
  if (tid == 0) red[5] = red[0] + red[1] + red[2] + red[3];
  __syncthreads();
  sc[tid] = e * (1.f / red[5]);
  __syncthreads();

  {
    float a0 = 0.f, a1 = 0.f;
    const __half2* base = (const __half2*)(enc_out + (size_t)b * Sv * Hv) + tid;
#pragma unroll 4
    for (int s2 = 0; s2 < Sv; ++s2) {
      unsigned uv = __builtin_bit_cast(unsigned, base[s2 * (Hv / 2)]) ^ ENC_KEY;
      float2 f = __half22float2(__builtin_bit_cast(__half2, uv));
      float w = sc[s2];
      a0 += w * f.x;
      a1 += w * f.y;
    }
    ctx[2 * tid] = a0;
    ctx[2 * tid + 1] = a1;
  }
  __syncthreads();

  if (tid < 88) {
    const float* wr = (tid < 8) ? (Wa + tid * Hv) : (Wt + (tid - 8) * Hv);
    float o = (tid < 8) ? ba[tid] : bt[tid - 8];
    for (int k = 0; k < Hv; ++k) o += ctx[k] * wr[k];
    if (tid < 8) {
      float* o0 = out + (size_t)b * Tv * 8;
#pragma unroll
      for (int t = 0; t < Tv; ++t) o0[t * 8 + tid] = o;
    } else {
      int n = tid - 8;
      float* o1 = out + 65536 + (size_t)b * Tv * 80;
#pragma unroll
      for (int t = 0; t < Tv; ++t) o1[t * 80 + n] = o;
    }
  }
}

extern "C" void kernel_launch(void* const* d_in, const int* in_sizes, int n_in,
                              void* d_out, int out_size, void* d_ws, size_t ws_size,
                              hipStream_t stream)
{
  (void)in_sizes; (void)n_in; (void)out_size; (void)ws_size;
  const int*   enc_in = (const int*)d_in[0];
  const float* embed  = (const float*)d_in[2];
  const float* Wi     = (const float*)d_in[3];
  const float* Wh     = (const float*)d_in[4];
  const float* be     = (const float*)d_in[5];
  const float* Wa     = (const float*)d_in[11];
  const float* ba     = (const float*)d_in[12];
  const float* Wt     = (const float*)d_in[13];
  const float* bt     = (const float*)d_in[14];
  const float* Wf     = (const float*)d_in[15];
  // d_in[1] decoder_target, [6..10] decoder weights, [16] bf: dead code

  char* ws = (char*)d_ws;
  float*  P      = (float*)ws;                       // 1000 x 2048 fp32 = 8MB
  __half* encout = (__half*)(ws + (8u << 20));       // 256x256x512 fp16 = 64MB (write-once exchange)

  // enc_out must be zero (poll sentinel) each run; encoded stores are never 0.
  hipMemsetAsync(encout, 0, 64u << 20, stream);

  build_P<<<dim3(250), dim3(256), 0, stream>>>(embed, Wi, be, P);
  lstm_enc<<<dim3(256), dim3(256), 0, stream>>>(enc_in, P, Wh, encout);
  attn_out<<<dim3(256), dim3(256), 0, stream>>>(encout, Wf, Wa, ba, Wt, bt, (float*)d_out);
}